// Round 1
// baseline (2824.800 us; speedup 1.0000x reference)
//
#include <hip/hip_runtime.h>
#include <hip/hip_bf16.h>
#include <cstdint>
#include <cstddef>

// Problem constants
#define T_TOK 4096
#define HID   4096
#define INT_  14336
#define RNK   318
#define RP    384     // rank padded to multiple of 128 (N) / 64 (K)

typedef __hip_bfloat16 bf16;
typedef __attribute__((ext_vector_type(8))) __bf16 bf16x8;
typedef __attribute__((ext_vector_type(4))) float  f32x4;

// ---------------------------------------------------------------------------
// async global->LDS, 16B per lane. LDS dest is wave-uniform base + lane*16.
__device__ __forceinline__ void gload16(const bf16* g, void* l) {
  __builtin_amdgcn_global_load_lds(
      (__attribute__((address_space(1))) void*)(uintptr_t)(const void*)g,
      (__attribute__((address_space(3))) void*)l,
      16, 0, 0);
}

// ---------------------------------------------------------------------------
// fp32 -> bf16 bulk convert (n divisible by 4)
__global__ void k_convert(const float* __restrict__ s, bf16* __restrict__ d, long n) {
  long i = ((long)blockIdx.x * blockDim.x + threadIdx.x) * 4;
  long stride = (long)gridDim.x * blockDim.x * 4;
  for (; i < n; i += stride) {
    float4 v = *(const float4*)(s + i);
    __hip_bfloat162 p0 = __float22bfloat162_rn(make_float2(v.x, v.y));
    __hip_bfloat162 p1 = __float22bfloat162_rn(make_float2(v.z, v.w));
    *(__hip_bfloat162*)(d + i)     = p0;
    *(__hip_bfloat162*)(d + i + 2) = p1;
  }
}

// fp32 -> bf16 with zero-padding to (dst_rows x dcols) from (srows x scols)
__global__ void k_convert_pad(const float* __restrict__ s, bf16* __restrict__ d,
                              int srows, int scols, int dcols, long total) {
  long i = (long)blockIdx.x * blockDim.x + threadIdx.x;
  long stride = (long)gridDim.x * blockDim.x;
  for (; i < total; i += stride) {
    int r = (int)(i / dcols), c = (int)(i % dcols);
    float v = (r < srows && c < scols) ? s[(long)r * scols + c] : 0.f;
    d[i] = __float2bfloat16(v);
  }
}

// ---------------------------------------------------------------------------
// C[M,N] = A[M,K] @ B[N,K]^T  (two K-segments: main weights + low-rank)
// 128x128 tile, BK=64, 256 threads = 4 waves, each wave 64x64 via 4x4 MFMA
// 16x16x32 bf16 tiles. global_load_lds staging with XOR-swizzled LDS layout
// (swizzle applied on the *source* address; LDS dest is lane-ordered).
// EPI: 0 = store bf16, 1 = z = silu(acc)*Up -> bf16, 2 = store fp32
template <int EPI>
__global__ __launch_bounds__(256)
void k_gemm(const bf16* __restrict__ A0, const bf16* __restrict__ B0, int K0,
            const bf16* __restrict__ A1, const bf16* __restrict__ B1, int K1,
            int N, void* __restrict__ Cout, const bf16* __restrict__ Up) {
  __shared__ __align__(128) bf16 As[128 * 64];
  __shared__ __align__(128) bf16 Bs[128 * 64];

  const int tid  = threadIdx.x;
  const int wv   = tid >> 6;
  const int lane = tid & 63;
  const int quad = lane >> 4;
  const int m16  = lane & 15;
  const int row0 = blockIdx.y * 128;
  const int col0 = blockIdx.x * 128;
  const int wrow = (wv >> 1) * 64;   // wave's 64x64 sub-tile
  const int wcol = (wv & 1) * 64;

  // staging lane mapping: 8 rows per wave-load, 8 chunks (16B) per row,
  // stored chunk s holds logical chunk q = s ^ (row&7)
  const int srow = lane >> 3;              // 0..7
  const int sq   = (lane & 7) ^ srow;      // swizzled source chunk

  // LDS byte offsets of each wave-tile fragment (kstep 0); kstep 1 = ^64
  int a_off[4], b_off[4];
#pragma unroll
  for (int i = 0; i < 4; i++) {
    int r = wrow + i * 16 + m16;
    a_off[i] = r * 128 + ((quad ^ (r & 7)) << 4);
    int c = wcol + i * 16 + m16;
    b_off[i] = c * 128 + ((quad ^ (c & 7)) << 4);
  }

  f32x4 acc[4][4] = {};

  const bf16* Aseg = A0;
  const bf16* Bseg = B0;
  int Ks = K0;
#pragma unroll 1
  for (int seg = 0; seg < 2; seg++) {
    if (seg) {
      if (K1 == 0) break;
      Aseg = A1; Bseg = B1; Ks = K1;
    }
    const int nkb = Ks >> 6;
#pragma unroll 1
    for (int kb = 0; kb < nkb; kb++) {
      __syncthreads();  // protect LDS from previous iteration's readers
#pragma unroll
      for (int i = 0; i < 4; i++) {
        const int wl = (wv << 2) + i;       // wave-load index 0..15
        const int r  = (wl << 3) + srow;    // tile row 0..127
        gload16(Aseg + (size_t)(row0 + r) * Ks + (kb << 6) + (sq << 3),
                (char*)As + wl * 1024);
        gload16(Bseg + (size_t)(col0 + r) * Ks + (kb << 6) + (sq << 3),
                (char*)Bs + wl * 1024);
      }
      __syncthreads();  // compiler emits vmcnt(0) drain here (m97 structure)
#pragma unroll
      for (int s = 0; s < 2; s++) {
        bf16x8 af[4], bfr[4];
#pragma unroll
        for (int i = 0; i < 4; i++)
          af[i] = *(const bf16x8*)((const char*)As + (a_off[i] ^ (s << 6)));
#pragma unroll
        for (int j = 0; j < 4; j++)
          bfr[j] = *(const bf16x8*)((const char*)Bs + (b_off[j] ^ (s << 6)));
#pragma unroll
        for (int i = 0; i < 4; i++)
#pragma unroll
          for (int j = 0; j < 4; j++)
            acc[i][j] = __builtin_amdgcn_mfma_f32_16x16x32_bf16(
                af[i], bfr[j], acc[i][j], 0, 0, 0);
      }
    }
  }

  // Epilogue. C/D layout: col = lane&15, row = quad*4 + r  [m89-verified]
#pragma unroll
  for (int i = 0; i < 4; i++) {
#pragma unroll
    for (int j = 0; j < 4; j++) {
      const int cc = col0 + wcol + j * 16 + m16;
#pragma unroll
      for (int r = 0; r < 4; r++) {
        const int rr = row0 + wrow + i * 16 + quad * 4 + r;
        const size_t idx = (size_t)rr * N + cc;
        float v = acc[i][j][r];
        if (EPI == 0) {
          ((bf16*)Cout)[idx] = __float2bfloat16(v);
        } else if (EPI == 1) {
          float u  = __bfloat162float(Up[idx]);
          float sg = v / (1.f + __expf(-v));
          ((bf16*)Cout)[idx] = __float2bfloat16(sg * u);
        } else {
          ((float*)Cout)[idx] = v;
        }
      }
    }
  }
}

// ---------------------------------------------------------------------------
extern "C" void kernel_launch(void* const* d_in, const int* in_sizes, int n_in,
                              void* d_out, int out_size, void* d_ws, size_t ws_size,
                              hipStream_t stream) {
  const float* x   = (const float*)d_in[0];
  const float* W1  = (const float*)d_in[1];
  const float* W2  = (const float*)d_in[2];
  const float* W3  = (const float*)d_in[3];
  const float* du1 = (const float*)d_in[4];
  const float* dv1 = (const float*)d_in[5];
  const float* du2 = (const float*)d_in[6];
  const float* dv2 = (const float*)d_in[7];
  const float* du3 = (const float*)d_in[8];
  const float* dv3 = (const float*)d_in[9];

  bf16* p = (bf16*)d_ws;
  bf16* xb   = p; p += (size_t)T_TOK * HID;
  bf16* W1b  = p; p += (size_t)INT_ * HID;
  bf16* W2b  = p; p += (size_t)HID * INT_;
  bf16* W3b  = p; p += (size_t)INT_ * HID;
  bf16* du1b = p; p += (size_t)INT_ * RP;
  bf16* dv1b = p; p += (size_t)RP * HID;
  bf16* du2b = p; p += (size_t)HID * RP;
  bf16* dv2b = p; p += (size_t)RP * INT_;
  bf16* du3b = p; p += (size_t)INT_ * RP;
  bf16* dv3b = p; p += (size_t)RP * HID;
  bf16* t1b  = p; p += (size_t)T_TOK * RP;
  bf16* t2b  = p; p += (size_t)T_TOK * RP;
  bf16* t3b  = p; p += (size_t)T_TOK * RP;
  bf16* upb  = p; p += (size_t)T_TOK * INT_;
  bf16* zb   = p; p += (size_t)T_TOK * INT_;

  // --- fp32 -> bf16 conversions (weights/activations), zero-padded ranks ---
  k_convert<<<8192, 256, 0, stream>>>(x,  xb,  (long)T_TOK * HID);
  k_convert<<<8192, 256, 0, stream>>>(W1, W1b, (long)INT_ * HID);
  k_convert<<<8192, 256, 0, stream>>>(W2, W2b, (long)HID * INT_);
  k_convert<<<8192, 256, 0, stream>>>(W3, W3b, (long)INT_ * HID);
  k_convert_pad<<<4096, 256, 0, stream>>>(du1, du1b, INT_, RNK, RP,  (long)INT_ * RP);
  k_convert_pad<<<4096, 256, 0, stream>>>(dv1, dv1b, RNK, HID, HID,  (long)RP * HID);
  k_convert_pad<<<4096, 256, 0, stream>>>(du2, du2b, HID, RNK, RP,   (long)HID * RP);
  k_convert_pad<<<4096, 256, 0, stream>>>(dv2, dv2b, RNK, INT_, INT_,(long)RP * INT_);
  k_convert_pad<<<4096, 256, 0, stream>>>(du3, du3b, INT_, RNK, RP,  (long)INT_ * RP);
  k_convert_pad<<<4096, 256, 0, stream>>>(dv3, dv3b, RNK, HID, HID,  (long)RP * HID);

  // --- t3 = x @ dv3^T, t1 = x @ dv1^T  (bf16 [T, RP], pads come out zero) ---
  k_gemm<0><<<dim3(RP / 128, T_TOK / 128), 256, 0, stream>>>(
      xb, dv3b, HID, nullptr, nullptr, 0, RP, t3b, nullptr);
  k_gemm<0><<<dim3(RP / 128, T_TOK / 128), 256, 0, stream>>>(
      xb, dv1b, HID, nullptr, nullptr, 0, RP, t1b, nullptr);

  // --- up = x@W3^T + t3@du3^T  (two-segment K) ---
  k_gemm<0><<<dim3(INT_ / 128, T_TOK / 128), 256, 0, stream>>>(
      xb, W3b, HID, t3b, du3b, RP, INT_, upb, nullptr);

  // --- z = silu(x@W1^T + t1@du1^T) * up  (fused epilogue) ---
  k_gemm<1><<<dim3(INT_ / 128, T_TOK / 128), 256, 0, stream>>>(
      xb, W1b, HID, t1b, du1b, RP, INT_, zb, upb);

  // --- t2 = z @ dv2^T ---
  k_gemm<0><<<dim3(RP / 128, T_TOK / 128), 256, 0, stream>>>(
      zb, dv2b, INT_, nullptr, nullptr, 0, RP, t2b, nullptr);

  // --- out = z@W2^T + t2@du2^T  (fp32 to d_out) ---
  k_gemm<2><<<dim3(HID / 128, T_TOK / 128), 256, 0, stream>>>(
      zb, W2b, INT_, t2b, du2b, RP, HID, d_out, nullptr);
}